// Round 1
// 186.075 us; speedup vs baseline: 1.0550x; 1.0550x over previous
//
#include <hip/hip_runtime.h>

// Problem constants
#define BATCH 2
#define SEQ   2048
#define DIM   1024
#define NHEAD 16
#define HD    64
#define BH    (BATCH * NHEAD)   // 32
#define SCALE 0.125f            // 64^-0.5
#define LOG2E 1.44269504f
#define NT128 (SEQ / 128)       // 16 k-tiles of 128 keys

typedef __attribute__((ext_vector_type(8))) short short8;
typedef __attribute__((ext_vector_type(4))) float f32x4;
typedef __attribute__((ext_vector_type(16))) float f32x16;
typedef __attribute__((ext_vector_type(2))) unsigned int uint2v;

#define MFMA16(a, b, c) __builtin_amdgcn_mfma_f32_16x16x32_bf16(a, b, c, 0, 0, 0)
#define MFMA32(a, b, c) __builtin_amdgcn_mfma_f32_32x32x16_bf16(a, b, c, 0, 0, 0)

__device__ __forceinline__ ushort f2bf(float f) {
    union { float f; unsigned u; } v;
    v.f = f;
    unsigned r = (v.u + 0x7FFF + ((v.u >> 16) & 1)) >> 16;   // RNE
    return (ushort)r;
}

__device__ __forceinline__ uint4 ld8f_bf16(const float* p) {
    float4 f0 = *(const float4*)p;
    float4 f1 = *(const float4*)(p + 4);
    union { ushort us[8]; uint4 v; } u;
    u.us[0] = f2bf(f0.x); u.us[1] = f2bf(f0.y);
    u.us[2] = f2bf(f0.z); u.us[3] = f2bf(f0.w);
    u.us[4] = f2bf(f1.x); u.us[5] = f2bf(f1.y);
    u.us[6] = f2bf(f1.z); u.us[7] = f2bf(f1.w);
    return u.v;
}

// async global->LDS, 16B/lane: lane i's 16B lands at l + i*16 (l wave-uniform)
__device__ __forceinline__ void gl_lds16(const ushort* g, ushort* l) {
    __builtin_amdgcn_global_load_lds(
        (const __attribute__((address_space(1))) unsigned int*)g,
        (__attribute__((address_space(3))) unsigned int*)l,
        16, 0, 0);
}

// ---------------------------------------------------------------------------
// fp32 -> bf16 bulk convert: x | qkv_w | proj_w
// ---------------------------------------------------------------------------
#define N_X  (BATCH * SEQ * DIM)       // 4194304
#define N_QW (3 * DIM * DIM)           // 3145728
#define N_PW (DIM * DIM)               // 1048576

__global__ __launch_bounds__(256) void cvt_kernel(
    const float* __restrict__ x, const float* __restrict__ qw,
    const float* __restrict__ pw, ushort* __restrict__ xb,
    ushort* __restrict__ qwb, ushort* __restrict__ pwb)
{
    const int i = (blockIdx.x * 256 + threadIdx.x) * 8;
    if (i < N_X)  *(uint4*)(xb  + i) = ld8f_bf16(x  + i);
    if (i < N_QW) *(uint4*)(qwb + i) = ld8f_bf16(qw + i);
    if (i < N_PW) *(uint4*)(pwb + i) = ld8f_bf16(pw + i);
}

// ---------------------------------------------------------------------------
// GEMM: C[M,N] = A[M,K] @ W[N,K]^T + bias[N], A/W bf16, bias fp32.
// Block tile: (2*WM*16) x 128, BK=32, 4 waves (2x2), wave tile (WM*16) x 64.
// Double-buffered LDS, one barrier per k-iter, DMA prefetch after barrier.
// MODE 0: scatter bf16 -> Q (pre-scaled by SCALE*LOG2E), K as [BH][SEQ][HD];
//         V transposed as [BH][HD][SEQ]
// MODE 1: fp32 row-major out [M,N]
// ---------------------------------------------------------------------------
template <int MODE, int WM, typename TOUT>
__global__ __launch_bounds__(256, 2) void gemm_bt(
    const ushort* __restrict__ A, const ushort* __restrict__ W,
    const float* __restrict__ bias, TOUT* __restrict__ out,
    int M, int Nout, int K)
{
    constexpr int BM = 2 * WM * 16;                 // block rows (128 or 64)
    __shared__ __align__(16) ushort As[2][BM * 32];
    __shared__ __align__(16) ushort Bs[2][128 * 32];

    const int tid  = threadIdx.x;
    const int wave = tid >> 6, lane = tid & 63;
    const int quad = lane >> 4, l16 = lane & 15;
    const int wm = wave >> 1, wn = wave & 1;
    const int m0 = blockIdx.y * BM, n0 = blockIdx.x * 128;

    const int c0 = tid, c1 = tid + 256;
    const ushort* gA0 = A + (size_t)(m0 + (c0 >> 2)) * K + (c0 & 3) * 8;
    const ushort* gA1 = A + (size_t)(m0 + (c1 >> 2)) * K + (c1 & 3) * 8;  // WM==4 only
    const ushort* gB0 = W + (size_t)(n0 + (c0 >> 2)) * K + (c0 & 3) * 8;
    const ushort* gB1 = W + (size_t)(n0 + (c1 >> 2)) * K + (c1 & 3) * 8;

#define STAGE_G(buf, k0)                                                  \
    {                                                                     \
        gl_lds16(gA0 + (k0), &As[buf][(wave * 64) * 8]);                  \
        if (WM == 4) gl_lds16(gA1 + (k0), &As[buf][(wave * 64 + 256) * 8]); \
        gl_lds16(gB0 + (k0), &Bs[buf][(wave * 64) * 8]);                  \
        gl_lds16(gB1 + (k0), &Bs[buf][(wave * 64 + 256) * 8]);            \
    }

    f32x4 acc[WM][4];
#pragma unroll
    for (int i = 0; i < WM; i++)
#pragma unroll
        for (int j = 0; j < 4; j++) acc[i][j] = (f32x4){0.f, 0.f, 0.f, 0.f};

    const int KT = K >> 5;
    STAGE_G(0, 0)

    for (int kt = 0; kt < KT; kt++) {
        const int cur = kt & 1;
        __syncthreads();
        if (kt + 1 < KT) STAGE_G(cur ^ 1, (kt + 1) * 32)

        short8 af[WM], bfr[4];
#pragma unroll
        for (int mt = 0; mt < WM; mt++)
            af[mt] = *(const short8*)&As[cur][(wm * (WM * 16) + mt * 16 + l16) * 32 + quad * 8];
#pragma unroll
        for (int nt = 0; nt < 4; nt++)
            bfr[nt] = *(const short8*)&Bs[cur][(wn * 64 + nt * 16 + l16) * 32 + quad * 8];
#pragma unroll
        for (int mt = 0; mt < WM; mt++)
#pragma unroll
            for (int nt = 0; nt < 4; nt++)
                acc[mt][nt] = MFMA16(af[mt], bfr[nt], acc[mt][nt]);
    }

#pragma unroll
    for (int nt = 0; nt < 4; nt++) {
        const int n = n0 + wn * 64 + nt * 16 + l16;
        const float bv = bias[n];
#pragma unroll
        for (int mt = 0; mt < WM; mt++) {
            const int mBase = m0 + wm * (WM * 16) + mt * 16 + quad * 4;
#pragma unroll
            for (int r = 0; r < 4; r++) {
                const int m = mBase + r;
                float v = acc[mt][nt][r] + bv;
                if (MODE == 0) {
                    const int which = n >> 10, rem = n & 1023;
                    const int h = rem >> 6, d = rem & 63;
                    const int b = m >> 11, nq = m & 2047;
                    const int bh = b * NHEAD + h;
                    if (which == 0) v *= (SCALE * LOG2E);  // fold scale+log2e into Q
                    size_t idx;
                    if (which == 2)   // V transposed: [BH][HD][SEQ]
                        idx = (size_t)2 * BH * SEQ * HD + ((size_t)bh * HD + d) * SEQ + nq;
                    else              // Q,K: [BH][SEQ][HD]
                        idx = (size_t)which * BH * SEQ * HD + ((size_t)bh * SEQ + nq) * HD + d;
                    ((ushort*)out)[idx] = f2bf(v);
                } else {
                    ((float*)out)[(size_t)m * Nout + n] = v;
                }
            }
        }
    }
#undef STAGE_G
}

// ---------------------------------------------------------------------------
// Flash attention, 32x32 MFMA "swapped" schedule:
//   4 waves x 32 q-rows = 128 q-rows per 256-thread block, grid 512 (XCD swz).
//   Per 128-key tile (two 64-key halves, ONE barrier):
//     S^T = mfma(K, Q)  -> each lane holds a full P-row (q = lane&31) in regs
//     p = exp2(s); P -> bf16 A-frags entirely in-register via
//     v_cvt_pk_bf16_f32 + permlane32_swap (T12) -- NO P LDS round-trip.
//   LDS traffic per 128 q-rows: 176KB -> 80KB vs the 16x16 version.
// ---------------------------------------------------------------------------
__global__ __launch_bounds__(256, 2) void attn_kernel(
    const ushort* __restrict__ qkv, ushort* __restrict__ wa)
{
    __shared__ __align__(16) ushort Ks[2][2][64 * 64];   // [buf][half][key][d] swz
    __shared__ __align__(16) ushort Vs[2][2][64 * 64];   // [buf][half][d][key] swz

    const int tid  = threadIdx.x;
    const int wave = tid >> 6, lane = tid & 63;          // wave 0..3
    const int l31  = lane & 31, hb = lane >> 5;

    // XCD swizzle: l%8 == bh%8 -> all 16 q-blocks of a head on one XCD
    const int l = blockIdx.x;
    const int bh = (l & 7) + 8 * (l >> 7);
    const int qi = (l >> 3) & 15;
    const int b = bh >> 4, head = bh & 15;

    const size_t hOff = (size_t)bh * SEQ * HD;
    const ushort* Q  = qkv + hOff;
    const ushort* Kg = qkv + (size_t)BH * SEQ * HD + hOff;
    const ushort* Vt = qkv + (size_t)2 * BH * SEQ * HD + hOff;   // [HD][SEQ]
    const int q0 = qi * 128 + wave * 32;

    // Q B-frags (pre-scaled by SCALE*LOG2E in GEMM): row q0+l31, d = i*16+hb*8
    short8 qf[4];
#pragma unroll
    for (int i = 0; i < 4; i++)
        qf[i] = *(const short8*)&Q[(size_t)(q0 + l31) * HD + i * 16 + hb * 8];

    f32x16 o0, o1;
#pragma unroll
    for (int r = 0; r < 16; r++) { o0[r] = 0.f; o1[r] = 0.f; }
    float lsum = 0.f;

    // DMA source swizzle: chunk stored at physical p = c ^ (row & 7)
    const int rr = lane >> 3;
    const int cc = ((lane & 7) ^ rr) * 8;
    const ushort* KgL = Kg + rr * HD + cc;
    const ushort* VtL = Vt + (size_t)rr * SEQ + cc;

    // wave stages 16 K rows + 16 V^T rows per 64-half: 8 DMAs / wave / k-tile
#define STAGE(buf, kt)                                                          \
    {                                                                           \
        const size_t kO = (size_t)(kt) * 128;                                   \
        gl_lds16(KgL + (kO +      wave * 16    ) * HD, &Ks[buf][0][(wave*16    ) * 64]); \
        gl_lds16(KgL + (kO +      wave * 16 + 8) * HD, &Ks[buf][0][(wave*16 + 8) * 64]); \
        gl_lds16(KgL + (kO + 64 + wave * 16    ) * HD, &Ks[buf][1][(wave*16    ) * 64]); \
        gl_lds16(KgL + (kO + 64 + wave * 16 + 8) * HD, &Ks[buf][1][(wave*16 + 8) * 64]); \
        gl_lds16(VtL + (size_t)(wave*16    ) * SEQ + kO,      &Vs[buf][0][(wave*16    ) * 64]); \
        gl_lds16(VtL + (size_t)(wave*16 + 8) * SEQ + kO,      &Vs[buf][0][(wave*16 + 8) * 64]); \
        gl_lds16(VtL + (size_t)(wave*16    ) * SEQ + kO + 64, &Vs[buf][1][(wave*16    ) * 64]); \
        gl_lds16(VtL + (size_t)(wave*16 + 8) * SEQ + kO + 64, &Vs[buf][1][(wave*16 + 8) * 64]); \
    }

    STAGE(0, 0)

    const int swz = l31 & 7;   // (row&7) for rows l31 and 32+l31

    for (int kt = 0; kt < NT128; kt++) {
        const int cur = kt & 1;
        __syncthreads();                  // staging(cur) complete (vmcnt drain)
        if (kt + 1 < NT128) STAGE(cur ^ 1, kt + 1)

#pragma unroll
        for (int hh = 0; hh < 2; hh++) {
            const ushort* kb_ = &Ks[cur][hh][0];
            const ushort* vb_ = &Vs[cur][hh][0];

            // S^T = K Q^T : lane holds S[q=l31][key = 32kb + (r&3)+8(r>>2)+4hb]
            f32x16 z[2];
#pragma unroll
            for (int kb = 0; kb < 2; kb++)
#pragma unroll
                for (int r = 0; r < 16; r++) z[kb][r] = 0.f;

            __builtin_amdgcn_s_setprio(1);
#pragma unroll
            for (int i = 0; i < 4; i++) {
                short8 ka0 = *(const short8*)&kb_[(l31     ) * 64 + (((2*i + hb) ^ swz) * 8)];
                short8 ka1 = *(const short8*)&kb_[(32 + l31) * 64 + (((2*i + hb) ^ swz) * 8)];
                z[0] = MFMA32(ka0, qf[i], z[0]);
                z[1] = MFMA32(ka1, qf[i], z[1]);
            }
            __builtin_amdgcn_s_setprio(0);

            // fixed-base softmax numerator + in-register bf16 pack
            unsigned u[2][8];
#pragma unroll
            for (int kb = 0; kb < 2; kb++) {
#pragma unroll
                for (int r = 0; r < 16; r++) {
                    const float pv = __builtin_amdgcn_exp2f(z[kb][r]);
                    z[kb][r] = pv;
                    lsum += pv;
                }
#pragma unroll
                for (int m = 0; m < 8; m++) {
                    unsigned pk;
                    asm("v_cvt_pk_bf16_f32 %0, %1, %2"
                        : "=v"(pk) : "v"(z[kb][2*m]), "v"(z[kb][2*m + 1]));
                    u[kb][m] = pk;
                }
            }

            // PV: A-frags via permlane32_swap; B = V^T rows (d), k = keys
            __builtin_amdgcn_s_setprio(1);
#pragma unroll
            for (int i = 0; i < 4; i++) {
                const int kb = i >> 1, ii = i & 1;
                uint2v s0 = __builtin_amdgcn_permlane32_swap(
                    u[kb][4*ii + 0], u[kb][4*ii + 2], false, false);
                uint2v s1 = __builtin_amdgcn_permlane32_swap(
                    u[kb][4*ii + 1], u[kb][4*ii + 3], false, false);
                union { unsigned w[4]; short8 s; } pf;
                pf.w[0] = s0[0]; pf.w[1] = s1[0]; pf.w[2] = s0[1]; pf.w[3] = s1[1];
                short8 vb0 = *(const short8*)&vb_[(l31     ) * 64 + (((2*i + hb) ^ swz) * 8)];
                short8 vb1 = *(const short8*)&vb_[(32 + l31) * 64 + (((2*i + hb) ^ swz) * 8)];
                o0 = MFMA32(pf.s, vb0, o0);
                o1 = MFMA32(pf.s, vb1, o1);
            }
            __builtin_amdgcn_s_setprio(0);
        }
    }

    // row sums: lane's 32 p-values all belong to q-row l31; combine hb halves
    lsum += __shfl_xor(lsum, 32);
    const float invf = 1.f / lsum;

    // epilogue: o row = (r&3)+8*(r>>2)+4*hb, col d = l31 (o0) / 32+l31 (o1)
#pragma unroll
    for (int r = 0; r < 16; r++) {
        const int qr = (r & 3) + 8 * (r >> 2) + 4 * hb;
        const float iv = __shfl(invf, qr);
        ushort* dst = wa + ((size_t)(b * SEQ + q0 + qr)) * DIM + head * HD + l31;
        dst[0]  = f2bf(o0[r] * iv);
        dst[32] = f2bf(o1[r] * iv);
    }
#undef STAGE
}

// ---------------------------------------------------------------------------
extern "C" void kernel_launch(void* const* d_in, const int* in_sizes, int n_in,
                              void* d_out, int out_size, void* d_ws, size_t ws_size,
                              hipStream_t stream)
{
    const float* x      = (const float*)d_in[0];
    const float* qkv_w  = (const float*)d_in[1];
    const float* qkv_b  = (const float*)d_in[2];
    const float* proj_w = (const float*)d_in[3];
    const float* proj_b = (const float*)d_in[4];
    float* out = (float*)d_out;

    ushort* xb  = (ushort*)d_ws;
    ushort* qwb = xb  + (size_t)N_X;
    ushort* pwb = qwb + (size_t)N_QW;
    ushort* qkv = pwb + (size_t)N_PW;                 // 3*BH*SEQ*HD
    ushort* wa  = qkv + (size_t)3 * BH * SEQ * HD;    // B*SEQ*DIM

    const int M = BATCH * SEQ;   // 4096
    dim3 blk(256);

    cvt_kernel<<<dim3((N_X / 8 + 255) / 256), blk, 0, stream>>>(
        x, qkv_w, proj_w, xb, qwb, pwb);

    // QKV: 128x128 tiles, grid 24x32 = 768 blocks
    gemm_bt<0, 4, ushort><<<dim3((3 * DIM) / 128, M / 128), blk, 0, stream>>>(
        xb, qwb, qkv_b, qkv, M, 3 * DIM, DIM);

    // attn: 1-D grid 512, 256 threads (4 waves x 32 q-rows), XCD-swizzled
    attn_kernel<<<dim3(512), dim3(256), 0, stream>>>(qkv, wa);

    // proj: 64x128 tiles, grid 8x64 = 512 blocks (2/CU)
    gemm_bt<1, 2, float><<<dim3(DIM / 128, M / 64), blk, 0, stream>>>(
        wa, pwb, proj_b, out, M, DIM, DIM);
}